// Round 16
// baseline (362.998 us; speedup 1.0000x reference)
//
#include <hip/hip_runtime.h>

#define EPS_C 0.01f

typedef __attribute__((ext_vector_type(8))) short short8;
typedef __attribute__((ext_vector_type(4))) float f32x4;
typedef __attribute__((ext_vector_type(4))) unsigned short u16x4;
typedef __attribute__((ext_vector_type(8))) unsigned short u16x8;

// ---------- workspace layout (float offsets) ----------
#define WS_H    0        // 320*320
#define WS_C    102400   // 256*256  C0
#define WS_C2   167936   // 256*256  C1
#define WS_Y    233472   // 256*256
#define WS_RHS  299008   // 256*64
#define WS_D11  331776   // 64*64
#define WS_WFH  419840   // 256*352 u16 each, fragment-packed
#define WS_WFM  464896
#define WS_WFL  509952
#define WS_BBH  555008   // 64*288 u16 each, fragment-packed
#define WS_BBM  564224
#define WS_BBL  573440
#define WS_WG   582656   // 65536*64 fp32
#define WS_E0   4776960  // 64*64 fp32
#define WS_E1   4781056  // 64*64 fp32

__device__ __forceinline__ int wfoff(int n, int k) {
    return (((n >> 4) * 44 + (k >> 5) * 4 + ((k >> 3) & 3)) << 7) + ((n & 15) << 3) + (k & 7);
}
__device__ __forceinline__ int bboff(int n, int k) {
    return (((n >> 4) * 36 + (k >> 5) * 4 + ((k >> 3) & 3)) << 7) + ((n & 15) << 3) + (k & 7);
}

__device__ __forceinline__ unsigned short f2bf(float f) {
    unsigned int u = __float_as_uint(f);
    unsigned int r = (u + 0x7fffu + ((u >> 16) & 1u)) >> 16;
    return (unsigned short)r;
}
__device__ __forceinline__ float bf2f(unsigned short h) {
    return __uint_as_float(((unsigned int)h) << 16);
}
__device__ __forceinline__ void split1(float f, unsigned short& h, unsigned short& m, unsigned short& l) {
    h = f2bf(f);
    float r1 = f - bf2f(h);
    m = f2bf(r1);
    l = f2bf(r1 - bf2f(m));
}
__device__ __forceinline__ void split8(const float* v, short8& h8, short8& m8, short8& l8) {
#pragma unroll
    for (int j = 0; j < 8; ++j) {
        unsigned short h, m, l;
        split1(v[j], h, m, l);
        h8[j] = (short)h; m8[j] = (short)m; l8[j] = (short)l;
    }
}

// ---------------- setup: P and H builds ----------------
__global__ void k_build(const float* __restrict__ Xm, const float* __restrict__ XPm,
                        float* __restrict__ H, float* __restrict__ P) {
    int idx = blockIdx.x * 256 + threadIdx.x;
    if (idx < 102400) {
        int i = idx / 320, j = idx - i * 320;
        const float4* a = (const float4*)(Xm + i * 320);
        const float4* b = (const float4*)(Xm + j * 320);
        float s = 0.f;
        for (int k = 0; k < 80; ++k) {
            float4 va = a[k], vb = b[k];
            s += va.x * vb.x + va.y * vb.y + va.z * vb.z + va.w * vb.w;
        }
        H[idx] = (i == j) ? s + EPS_C : s;
    } else {
        idx -= 102400;
        if (idx < 65536) {
            int i = idx >> 8, j = idx & 255;
            const float4* a = (const float4*)(XPm + i * 256);
            const float4* b = (const float4*)(XPm + j * 256);
            float s = 0.f;
            for (int k = 0; k < 64; ++k) {
                float4 va = a[k], vb = b[k];
                s += va.x * vb.x + va.y * vb.y + va.z * vb.z + va.w * vb.w;
            }
            P[idx] = (i == j) ? s + EPS_C : s;
        }
    }
}

// ---------------- derived + packs + first inv8 (block 441) ----------------
__global__ void __launch_bounds__(256) k_derived(const float* __restrict__ H, const float* __restrict__ Um,
                          const float* __restrict__ Y1, const float* __restrict__ B2,
                          const float* __restrict__ D12,
                          float* __restrict__ Y, float* __restrict__ RHS,
                          float* __restrict__ D11g,
                          unsigned short* __restrict__ Bh, unsigned short* __restrict__ Bm,
                          unsigned short* __restrict__ Bl,
                          unsigned short* __restrict__ Bbh, unsigned short* __restrict__ Bbm,
                          unsigned short* __restrict__ Bbl,
                          const float* __restrict__ C0, float* __restrict__ E0) {
    __shared__ __align__(16) float M[64 * 68];
    __shared__ __align__(16) float Rs[8 * 68];
    __shared__ __align__(16) float Ts[64 * 8];
    __shared__ float E8s[8 * 9];
    const int tid = threadIdx.x;
    if (blockIdx.x == 441) { // inv8 of C0 block (0,0) -> E0
        const int ti = tid & 15, tj = tid >> 4;
#pragma unroll
        for (int t = 0; t < 4; ++t) {
            int e = tid + t * 256;
            int r = e >> 4, c4 = e & 15;
            float4 v = *(const float4*)&C0[(size_t)r * 256 + c4 * 4];
            *(float4*)&M[r * 68 + c4 * 4] = v;
        }
        __syncthreads();
        for (int s = 0; s < 8; ++s) {
            if (tid < 64) {
                const int lane = tid;
                float e8[8];
#pragma unroll
                for (int j = 0; j < 8; ++j) e8[j] = 0.f;
                if (lane < 8) {
#pragma unroll
                    for (int j = 0; j < 8; ++j) e8[j] = M[(s * 8 + lane) * 68 + s * 8 + j];
                }
#pragma unroll
                for (int k = 0; k < 8; ++k) {
                    const float p = __shfl(e8[k], k);
                    const float rinv = 1.0f / p;
                    const float f = -e8[k] * rinv;
                    const bool isk = (lane == k);
#pragma unroll
                    for (int j = 0; j < 8; ++j) {
                        const float prj = __shfl(e8[j], k);
                        if (j == k) e8[j] = isk ? rinv : f;
                        else        e8[j] = isk ? prj * rinv : fmaf(f, prj, e8[j]);
                    }
                }
                if (lane < 8) {
#pragma unroll
                    for (int j = 0; j < 8; ++j) E8s[lane * 9 + j] = e8[j];
                }
            }
            __syncthreads();
#pragma unroll
            for (int t = 0; t < 2; ++t) {
                int e = tid + t * 256;
                int r = e >> 6, c = e & 63;
                Rs[r * 68 + c] = M[(s * 8 + r) * 68 + c];
            }
#pragma unroll
            for (int t = 0; t < 2; ++t) {
                int e = tid + t * 256;
                int i = e >> 3, c = e & 7;
                float acc = 0.f;
#pragma unroll
                for (int j = 0; j < 8; ++j) acc = fmaf(M[i * 68 + s * 8 + j], E8s[j * 9 + c], acc);
                Ts[i * 8 + c] = acc;
            }
            __syncthreads();
            {
                const bool rowIn = ((ti >> 1) == s);
                const bool colIn = ((tj >> 1) == s);
                const int i0 = ti * 4, j0 = tj * 4;
                float nv[4][4];
                if (rowIn && colIn) {
#pragma unroll
                    for (int r = 0; r < 4; ++r)
#pragma unroll
                        for (int d = 0; d < 4; ++d)
                            nv[r][d] = E8s[(i0 - s * 8 + r) * 9 + (j0 - s * 8 + d)];
                } else if (rowIn) {
#pragma unroll
                    for (int r = 0; r < 4; ++r)
#pragma unroll
                        for (int d = 0; d < 4; ++d) {
                            float acc = 0.f;
#pragma unroll
                            for (int c = 0; c < 8; ++c)
                                acc = fmaf(E8s[(i0 - s * 8 + r) * 9 + c], Rs[c * 68 + j0 + d], acc);
                            nv[r][d] = acc;
                        }
                } else if (colIn) {
#pragma unroll
                    for (int r = 0; r < 4; ++r)
#pragma unroll
                        for (int d = 0; d < 4; ++d)
                            nv[r][d] = -Ts[(i0 + r) * 8 + (j0 - s * 8 + d)];
                } else {
#pragma unroll
                    for (int r = 0; r < 4; ++r)
#pragma unroll
                        for (int d = 0; d < 4; ++d) {
                            float acc = M[(i0 + r) * 68 + j0 + d];
#pragma unroll
                            for (int c = 0; c < 8; ++c)
                                acc = fmaf(-Ts[(i0 + r) * 8 + c], Rs[c * 68 + j0 + d], acc);
                            nv[r][d] = acc;
                        }
                }
#pragma unroll
                for (int r = 0; r < 4; ++r)
#pragma unroll
                    for (int d = 0; d < 4; ++d) M[(i0 + r) * 68 + j0 + d] = nv[r][d];
            }
            __syncthreads();
        }
#pragma unroll
        for (int t = 0; t < 4; ++t) {
            int e = tid + t * 256;
            int r = e >> 4, c4 = e & 15;
            float4 v = *(const float4*)&M[r * 68 + c4 * 4];
            *(float4*)&E0[(size_t)r * 64 + c4 * 4] = v;
        }
        return;
    }
    int idx = blockIdx.x * 256 + tid;
    if (idx < 65536) {
        int i = idx >> 8, j = idx & 255;
        Y[idx] = -0.5f * (H[i * 320 + j] + Y1[i * 256 + j] - Y1[j * 256 + i]);
        return;
    }
    idx -= 65536;
    if (idx < 16384) {
        RHS[idx] = -H[(idx >> 6) * 320 + 256 + (idx & 63)] - Um[idx];
        return;
    }
    idx -= 16384;
    if (idx < 4096) {
        int q = idx >> 6, j = idx & 63;
        float lam = 0.5f * H[(256 + q) * 320 + 256 + q];
        D11g[idx] = (j < q) ? -H[(256 + q) * 320 + 256 + j] / lam : 0.f;
        return;
    }
    idx -= 4096;
    if (idx < 8192) {
        int o = idx >> 5, cc = idx & 31;
        float f = (cc < 8) ? B2[o * 8 + cc] : 0.f;
        unsigned short h, m, l;
        split1(f, h, m, l);
        int off = wfoff(o, 256 + cc);
        Bh[off] = h; Bm[off] = m; Bl[off] = l;
        return;
    }
    idx -= 8192;
    if (idx < 18432) {
        int q = idx / 288, k = idx - q * 288;
        float f;
        if (k < 256) {
            float lam = 0.5f * H[(256 + q) * 320 + 256 + q];
            f = Um[(size_t)k * 64 + q] / lam;
        } else if (k < 264) f = D12[(size_t)q * 8 + (k - 256)];
        else f = 0.f;
        unsigned short h, m, l;
        split1(f, h, m, l);
        int off = bboff(q, k);
        Bbh[off] = h; Bbm[off] = m; Bbl[off] = l;
    }
}

// ---------------- GJ sweep + embedded inverse of next diag block (E double-buffered) --------
__global__ void __launch_bounds__(256) k_gjS(const float* __restrict__ Cold, float* __restrict__ Cnew,
                                             const float* __restrict__ E, float* __restrict__ Eout,
                                             int b, int nb) {
    const int I = blockIdx.x >> 2, J = blockIdx.x & 3;
    const int tid = threadIdx.x;
    const int ti = tid & 15, tj = tid >> 4;
    if (I == b && J == b) { // diag <- E
        const int r = tid >> 2, seg = tid & 3;
#pragma unroll
        for (int t = 0; t < 4; ++t) {
            float4 v = *(const float4*)&E[(size_t)r * 64 + seg * 16 + t * 4];
            *(float4*)&Cnew[(size_t)(b * 64 + r) * 256 + b * 64 + seg * 16 + t * 4] = v;
        }
        return;
    }
    __shared__ __align__(16) float Es[64 * 68];
    __shared__ __align__(16) float S1[64 * 68];
    __shared__ __align__(16) float S2[64 * 68];
    for (int e = tid; e < 1024; e += 256) {
        int r = e >> 4, c4 = e & 15;
        float4 v = *(const float4*)&E[(size_t)r * 64 + c4 * 4];
        *(float4*)&Es[r * 68 + c4 * 4] = v;
    }
    if (I == b) { // row block: W = E * Cold[b,J]
        for (int e = tid; e < 1024; e += 256) {
            int r = e >> 4, c4 = e & 15;
            float4 v = *(const float4*)&Cold[(size_t)(b * 64 + r) * 256 + J * 64 + c4 * 4];
            *(float4*)&S1[r * 68 + c4 * 4] = v;
        }
        __syncthreads();
        float acc[4][4];
#pragma unroll
        for (int r = 0; r < 4; ++r)
#pragma unroll
            for (int d = 0; d < 4; ++d) acc[r][d] = 0.f;
        for (int mm = 0; mm < 64; ++mm) {
            float a4[4], b4[4];
#pragma unroll
            for (int d = 0; d < 4; ++d) { a4[d] = Es[(ti * 4 + d) * 68 + mm]; b4[d] = S1[mm * 68 + tj * 4 + d]; }
#pragma unroll
            for (int r = 0; r < 4; ++r)
#pragma unroll
                for (int d = 0; d < 4; ++d) acc[r][d] = fmaf(a4[r], b4[d], acc[r][d]);
        }
#pragma unroll
        for (int r = 0; r < 4; ++r) {
            float4 v = {acc[r][0], acc[r][1], acc[r][2], acc[r][3]};
            *(float4*)&Cnew[(size_t)(b * 64 + ti * 4 + r) * 256 + J * 64 + tj * 4] = v;
        }
        return;
    }
    if (J == b) { // col block: -Cold[I,b] * E
        for (int e = tid; e < 1024; e += 256) {
            int r = e >> 4, c4 = e & 15;
            float4 v = *(const float4*)&Cold[(size_t)(I * 64 + r) * 256 + b * 64 + c4 * 4];
            *(float4*)&S1[r * 68 + c4 * 4] = v;
        }
        __syncthreads();
        float acc[4][4];
#pragma unroll
        for (int r = 0; r < 4; ++r)
#pragma unroll
            for (int d = 0; d < 4; ++d) acc[r][d] = 0.f;
        for (int kk = 0; kk < 64; ++kk) {
            float a4[4], b4[4];
#pragma unroll
            for (int d = 0; d < 4; ++d) { a4[d] = S1[(ti * 4 + d) * 68 + kk]; b4[d] = Es[kk * 68 + tj * 4 + d]; }
#pragma unroll
            for (int r = 0; r < 4; ++r)
#pragma unroll
                for (int d = 0; d < 4; ++d) acc[r][d] = fmaf(a4[r], b4[d], acc[r][d]);
        }
#pragma unroll
        for (int r = 0; r < 4; ++r) {
            float4 v = {-acc[r][0], -acc[r][1], -acc[r][2], -acc[r][3]};
            *(float4*)&Cnew[(size_t)(I * 64 + ti * 4 + r) * 256 + b * 64 + tj * 4] = v;
        }
        return;
    }
    // update tile
    for (int e = tid; e < 1024; e += 256) {
        int r = e >> 4, c4 = e & 15;
        float4 v = *(const float4*)&Cold[(size_t)(I * 64 + r) * 256 + b * 64 + c4 * 4];
        *(float4*)&S1[r * 68 + c4 * 4] = v;
        float4 w = *(const float4*)&Cold[(size_t)(b * 64 + r) * 256 + J * 64 + c4 * 4];
        *(float4*)&S2[r * 68 + c4 * 4] = w;
    }
    __syncthreads();
    float t4[4][4];
#pragma unroll
    for (int r = 0; r < 4; ++r)
#pragma unroll
        for (int d = 0; d < 4; ++d) t4[r][d] = 0.f;
    for (int kk = 0; kk < 64; ++kk) {
        float a4[4], b4[4];
#pragma unroll
        for (int d = 0; d < 4; ++d) { a4[d] = S1[(ti * 4 + d) * 68 + kk]; b4[d] = Es[kk * 68 + tj * 4 + d]; }
#pragma unroll
        for (int r = 0; r < 4; ++r)
#pragma unroll
            for (int d = 0; d < 4; ++d) t4[r][d] = fmaf(a4[r], b4[d], t4[r][d]);
    }
    __syncthreads();
#pragma unroll
    for (int r = 0; r < 4; ++r)
#pragma unroll
        for (int d = 0; d < 4; ++d) S1[(ti * 4 + r) * 68 + tj * 4 + d] = t4[r][d];
    __syncthreads();
    float acc[4][4];
#pragma unroll
    for (int r = 0; r < 4; ++r) {
        float4 cv = *(const float4*)&Cold[(size_t)(I * 64 + ti * 4 + r) * 256 + J * 64 + tj * 4];
        acc[r][0] = cv.x; acc[r][1] = cv.y; acc[r][2] = cv.z; acc[r][3] = cv.w;
    }
    for (int kk = 0; kk < 64; ++kk) {
        float a4[4], b4[4];
#pragma unroll
        for (int d = 0; d < 4; ++d) { a4[d] = S1[(ti * 4 + d) * 68 + kk]; b4[d] = S2[kk * 68 + tj * 4 + d]; }
#pragma unroll
        for (int r = 0; r < 4; ++r)
#pragma unroll
            for (int d = 0; d < 4; ++d) acc[r][d] = fmaf(-a4[r], b4[d], acc[r][d]);
    }
#pragma unroll
    for (int r = 0; r < 4; ++r) {
        float4 v = {acc[r][0], acc[r][1], acc[r][2], acc[r][3]};
        *(float4*)&Cnew[(size_t)(I * 64 + ti * 4 + r) * 256 + J * 64 + tj * 4] = v;
    }
    // embedded inverse of next sweep's diag block -> Eout
    if (I == nb && J == nb) {
        float* M   = Es;
        float* Rs2 = S2;
        float* Ts2 = S2 + 1024;
        float* E8s = S2 + 1664;
        __syncthreads();
#pragma unroll
        for (int r = 0; r < 4; ++r)
#pragma unroll
            for (int d = 0; d < 4; ++d)
                M[(ti * 4 + r) * 68 + tj * 4 + d] = acc[r][d];
        __syncthreads();
        for (int s = 0; s < 8; ++s) {
            if (tid < 64) {
                const int lane = tid;
                float e8[8];
#pragma unroll
                for (int j = 0; j < 8; ++j) e8[j] = 0.f;
                if (lane < 8) {
#pragma unroll
                    for (int j = 0; j < 8; ++j) e8[j] = M[(s * 8 + lane) * 68 + s * 8 + j];
                }
#pragma unroll
                for (int k = 0; k < 8; ++k) {
                    const float p = __shfl(e8[k], k);
                    const float rinv = 1.0f / p;
                    const float f = -e8[k] * rinv;
                    const bool isk = (lane == k);
#pragma unroll
                    for (int j = 0; j < 8; ++j) {
                        const float prj = __shfl(e8[j], k);
                        if (j == k) e8[j] = isk ? rinv : f;
                        else        e8[j] = isk ? prj * rinv : fmaf(f, prj, e8[j]);
                    }
                }
                if (lane < 8) {
#pragma unroll
                    for (int j = 0; j < 8; ++j) E8s[lane * 9 + j] = e8[j];
                }
            }
            __syncthreads();
#pragma unroll
            for (int t = 0; t < 2; ++t) {
                int e = tid + t * 256;
                int r = e >> 6, c = e & 63;
                Rs2[r * 68 + c] = M[(s * 8 + r) * 68 + c];
            }
#pragma unroll
            for (int t = 0; t < 2; ++t) {
                int e = tid + t * 256;
                int i = e >> 3, c = e & 7;
                float a2 = 0.f;
#pragma unroll
                for (int j = 0; j < 8; ++j) a2 = fmaf(M[i * 68 + s * 8 + j], E8s[j * 9 + c], a2);
                Ts2[i * 8 + c] = a2;
            }
            __syncthreads();
            {
                const bool rowIn = ((ti >> 1) == s);
                const bool colIn = ((tj >> 1) == s);
                const int i0 = ti * 4, j0 = tj * 4;
                float nv[4][4];
                if (rowIn && colIn) {
#pragma unroll
                    for (int r = 0; r < 4; ++r)
#pragma unroll
                        for (int d = 0; d < 4; ++d)
                            nv[r][d] = E8s[(i0 - s * 8 + r) * 9 + (j0 - s * 8 + d)];
                } else if (rowIn) {
#pragma unroll
                    for (int r = 0; r < 4; ++r)
#pragma unroll
                        for (int d = 0; d < 4; ++d) {
                            float a2 = 0.f;
#pragma unroll
                            for (int c = 0; c < 8; ++c)
                                a2 = fmaf(E8s[(i0 - s * 8 + r) * 9 + c], Rs2[c * 68 + j0 + d], a2);
                            nv[r][d] = a2;
                        }
                } else if (colIn) {
#pragma unroll
                    for (int r = 0; r < 4; ++r)
#pragma unroll
                        for (int d = 0; d < 4; ++d)
                            nv[r][d] = -Ts2[(i0 + r) * 8 + (j0 - s * 8 + d)];
                } else {
#pragma unroll
                    for (int r = 0; r < 4; ++r)
#pragma unroll
                        for (int d = 0; d < 4; ++d) {
                            float a2 = M[(i0 + r) * 68 + j0 + d];
#pragma unroll
                            for (int c = 0; c < 8; ++c)
                                a2 = fmaf(-Ts2[(i0 + r) * 8 + c], Rs2[c * 68 + j0 + d], a2);
                            nv[r][d] = a2;
                        }
                }
#pragma unroll
                for (int r = 0; r < 4; ++r)
#pragma unroll
                    for (int d = 0; d < 4; ++d) M[(i0 + r) * 68 + j0 + d] = nv[r][d];
            }
            __syncthreads();
        }
#pragma unroll
        for (int t = 0; t < 4; ++t) {
            int e = tid + t * 256;
            int r = e >> 4, c4 = e & 15;
            float4 v = *(const float4*)&M[r * 68 + c4 * 4];
            *(float4*)&Eout[(size_t)r * 64 + c4 * 4] = v;
        }
    }
}

// ---------------- apply: Wf cols = Pinv @ [Y | RHS], fragment-packed 3-way ----------------
__global__ void __launch_bounds__(256) k_apply2(const float* __restrict__ PI, const float* __restrict__ Y,
                                                const float* __restrict__ RHS,
                                                unsigned short* __restrict__ Bh, unsigned short* __restrict__ Bm,
                                                unsigned short* __restrict__ Bl) {
    const int i0 = ((int)blockIdx.x / 5) * 64;
    const int c0 = ((int)blockIdx.x % 5) * 64;
    __shared__ __align__(16) float S1[64 * 68], S2[64 * 68];
    const int tid = threadIdx.x;
    const int ti = tid & 15, tj = tid >> 4;
    float acc[4][4];
#pragma unroll
    for (int r = 0; r < 4; ++r)
#pragma unroll
        for (int d = 0; d < 4; ++d) acc[r][d] = 0.f;
    for (int kc = 0; kc < 4; ++kc) {
        __syncthreads();
        for (int e = tid; e < 1024; e += 256) {
            int i = e >> 4, k4 = e & 15;
            float4 v = *(const float4*)&PI[(size_t)(i0 + i) * 256 + kc * 64 + k4 * 4];
            S1[(k4 * 4 + 0) * 68 + i] = v.x;
            S1[(k4 * 4 + 1) * 68 + i] = v.y;
            S1[(k4 * 4 + 2) * 68 + i] = v.z;
            S1[(k4 * 4 + 3) * 68 + i] = v.w;
            float4 w;
            if (c0 < 256) w = *(const float4*)&Y[(size_t)(kc * 64 + i) * 256 + c0 + k4 * 4];
            else          w = *(const float4*)&RHS[(size_t)(kc * 64 + i) * 64 + k4 * 4];
            *(float4*)&S2[i * 68 + k4 * 4] = w;
        }
        __syncthreads();
        for (int kk = 0; kk < 64; ++kk) {
            float4 pv = *(const float4*)&S1[kk * 68 + ti * 4];
            float4 gv = *(const float4*)&S2[kk * 68 + tj * 4];
            float p4[4] = {pv.x, pv.y, pv.z, pv.w};
            float g4[4] = {gv.x, gv.y, gv.z, gv.w};
#pragma unroll
            for (int r = 0; r < 4; ++r)
#pragma unroll
                for (int d = 0; d < 4; ++d) acc[r][d] = fmaf(p4[r], g4[d], acc[r][d]);
        }
    }
    const int pc0 = (c0 < 256) ? c0 : 288;
#pragma unroll
    for (int r = 0; r < 4; ++r)
#pragma unroll
        for (int d = 0; d < 4; ++d) {
            unsigned short h, m, l;
            split1(acc[r][d], h, m, l);
            int off = wfoff(i0 + ti * 4 + r, pc0 + tj * 4 + d);
            Bh[off] = h; Bm[off] = m; Bl[off] = l;
        }
}

// ---------------- fused base + recurrence -> wg (fp32) ----------------
#define XSTR 264
__global__ void __launch_bounds__(256, 2) k_basrec(const float* __restrict__ x, const float* __restrict__ u,
                                                   const unsigned short* __restrict__ Bbh,
                                                   const unsigned short* __restrict__ Bbm,
                                                   const unsigned short* __restrict__ Bbl,
                                                   const float* __restrict__ bv,
                                                   const float* __restrict__ D11g,
                                                   float* __restrict__ wg) {
    __shared__ __align__(16) unsigned short Ah[32 * XSTR];
    __shared__ __align__(16) unsigned short Am[32 * XSTR];
    __shared__ __align__(16) unsigned short Al[32 * XSTR];
    __shared__ float bs[32 * 65];
    __shared__ float Ds[64 * 64];
    const int tid = threadIdx.x;
    const int r0 = blockIdx.x * 32;
    {
        const float4* xg4 = (const float4*)(x + (size_t)r0 * 256);
#pragma unroll
        for (int i = 0; i < 8; ++i) {
            int e = tid + i * 256, r = e >> 6, c4 = e & 63;
            float4 v = xg4[e];
            float vv[4] = {v.x, v.y, v.z, v.w};
            u16x4 hv, mv, lv;
#pragma unroll
            for (int j = 0; j < 4; ++j) {
                unsigned short h, m, l;
                split1(vv[j], h, m, l);
                hv[j] = h; mv[j] = m; lv[j] = l;
            }
            *(u16x4*)&Ah[r * XSTR + c4 * 4] = hv;
            *(u16x4*)&Am[r * XSTR + c4 * 4] = mv;
            *(u16x4*)&Al[r * XSTR + c4 * 4] = lv;
        }
#pragma unroll
        for (int t = 0; t < 16; ++t) Ds[tid + t * 256] = D11g[tid + t * 256];
    }
    __syncthreads();
    const int lane = tid & 63, wid = tid >> 6;
    const int n0 = wid * 16;
    const int lr = lane & 15, lg = lane >> 4;
    const int lk = lg * 8;
    const int fb = wid * 4608 + lg * 128 + lr * 8;
    f32x4 acc[2];
    acc[0] = (f32x4){0.f, 0.f, 0.f, 0.f};
    acc[1] = (f32x4){0.f, 0.f, 0.f, 0.f};
    for (int kt = 0; kt < 9; ++kt) {
        const int ka = kt * 32 + lk;
        short8 a_h[2], a_m[2], a_l[2];
        if (kt < 8) {
            a_h[0] = *(const short8*)&Ah[lr * XSTR + ka];
            a_h[1] = *(const short8*)&Ah[(16 + lr) * XSTR + ka];
            a_m[0] = *(const short8*)&Am[lr * XSTR + ka];
            a_m[1] = *(const short8*)&Am[(16 + lr) * XSTR + ka];
            a_l[0] = *(const short8*)&Al[lr * XSTR + ka];
            a_l[1] = *(const short8*)&Al[(16 + lr) * XSTR + ka];
        } else {
            if (lg == 0) {
                float vv[8];
                const float4* up = (const float4*)&u[(size_t)(r0 + lr) * 8];
                float4 v0 = up[0], v1 = up[1];
                vv[0] = v0.x; vv[1] = v0.y; vv[2] = v0.z; vv[3] = v0.w;
                vv[4] = v1.x; vv[5] = v1.y; vv[6] = v1.z; vv[7] = v1.w;
                split8(vv, a_h[0], a_m[0], a_l[0]);
                const float4* up2 = (const float4*)&u[(size_t)(r0 + 16 + lr) * 8];
                float4 w0 = up2[0], w1 = up2[1];
                vv[0] = w0.x; vv[1] = w0.y; vv[2] = w0.z; vv[3] = w0.w;
                vv[4] = w1.x; vv[5] = w1.y; vv[6] = w1.z; vv[7] = w1.w;
                split8(vv, a_h[1], a_m[1], a_l[1]);
            } else {
                short8 z = {0, 0, 0, 0, 0, 0, 0, 0};
                a_h[0] = z; a_h[1] = z; a_m[0] = z; a_m[1] = z; a_l[0] = z; a_l[1] = z;
            }
        }
        const int off = fb + kt * 512;
        short8 b_h = *(const short8*)&Bbh[off];
        short8 b_m = *(const short8*)&Bbm[off];
        short8 b_l = *(const short8*)&Bbl[off];
#pragma unroll
        for (int m = 0; m < 2; ++m) {
            acc[m] = __builtin_amdgcn_mfma_f32_16x16x32_bf16(a_h[m], b_h, acc[m], 0, 0, 0);
            acc[m] = __builtin_amdgcn_mfma_f32_16x16x32_bf16(a_m[m], b_h, acc[m], 0, 0, 0);
            acc[m] = __builtin_amdgcn_mfma_f32_16x16x32_bf16(a_h[m], b_m, acc[m], 0, 0, 0);
            acc[m] = __builtin_amdgcn_mfma_f32_16x16x32_bf16(a_l[m], b_h, acc[m], 0, 0, 0);
            acc[m] = __builtin_amdgcn_mfma_f32_16x16x32_bf16(a_m[m], b_m, acc[m], 0, 0, 0);
            acc[m] = __builtin_amdgcn_mfma_f32_16x16x32_bf16(a_h[m], b_l, acc[m], 0, 0, 0);
        }
    }
    {
        const float bvv = bv[n0 + lr];
#pragma unroll
        for (int m = 0; m < 2; ++m)
#pragma unroll
            for (int j = 0; j < 4; ++j)
                bs[(m * 16 + lg * 4 + j) * 65 + n0 + lr] = acc[m][j] + bvv;
    }
    __syncthreads();
    // recurrence: threads 0..31, row in registers
    if (tid < 32) {
        float w[64];
#pragma unroll
        for (int c = 0; c < 64; ++c) w[c] = bs[tid * 65 + c];
        w[0] = fmaxf(w[0], 0.f);
#pragma unroll
        for (int i = 1; i < 64; ++i) {
            float s0 = w[i], s1 = 0.f, s2 = 0.f, s3 = 0.f;
#pragma unroll
            for (int j = 0; j + 3 < i; j += 4) {
                s0 = fmaf(w[j + 0], Ds[i * 64 + j + 0], s0);
                s1 = fmaf(w[j + 1], Ds[i * 64 + j + 1], s1);
                s2 = fmaf(w[j + 2], Ds[i * 64 + j + 2], s2);
                s3 = fmaf(w[j + 3], Ds[i * 64 + j + 3], s3);
            }
#pragma unroll
            for (int j = i & ~3; j < i; ++j) s0 = fmaf(w[j], Ds[i * 64 + j], s0);
            w[i] = fmaxf((s0 + s1) + (s2 + s3), 0.f);
        }
        float* wr = wg + (size_t)(r0 + tid) * 64;
#pragma unroll
        for (int c = 0; c < 16; ++c) {
            float4 v = {w[4 * c], w[4 * c + 1], w[4 * c + 2], w[4 * c + 3]};
            *(float4*)&wr[c * 4] = v;
        }
    }
}

// ---------------- main 2: out = [x|u|0|w] @ Wf^T (packed-fragment B) ----------------
__global__ void __launch_bounds__(256, 3) k_m2(const float* __restrict__ x, const float* __restrict__ wg,
                                               const float* __restrict__ u,
                                               const unsigned short* __restrict__ Bh,
                                               const unsigned short* __restrict__ Bm,
                                               const unsigned short* __restrict__ Bl,
                                               float* __restrict__ out) {
    __shared__ __align__(16) unsigned short Ah[32 * XSTR];
    __shared__ __align__(16) unsigned short Am[32 * XSTR];
    __shared__ __align__(16) unsigned short Al[32 * XSTR];
    const int tid = threadIdx.x;
    const int r0 = blockIdx.x * 32;
    {
        const float4* xg4 = (const float4*)(x + (size_t)r0 * 256);
#pragma unroll
        for (int i = 0; i < 8; ++i) {
            int e = tid + i * 256, r = e >> 6, c4 = e & 63;
            float4 v = xg4[e];
            float vv[4] = {v.x, v.y, v.z, v.w};
            u16x4 hv, mv, lv;
#pragma unroll
            for (int j = 0; j < 4; ++j) {
                unsigned short h, m, l;
                split1(vv[j], h, m, l);
                hv[j] = h; mv[j] = m; lv[j] = l;
            }
            *(u16x4*)&Ah[r * XSTR + c4 * 4] = hv;
            *(u16x4*)&Am[r * XSTR + c4 * 4] = mv;
            *(u16x4*)&Al[r * XSTR + c4 * 4] = lv;
        }
    }
    __syncthreads();
    const int lane = tid & 63, wid = tid >> 6;
    const int n0 = wid * 64;
    const int lr = lane & 15, lg = lane >> 4;
    const int lk = lg * 8;
    const int lgoff = lg * 128 + lr * 8;
    int fb[4];
#pragma unroll
    for (int nf = 0; nf < 4; ++nf) fb[nf] = (wid * 4 + nf) * 5632 + lgoff;
    f32x4 acc[2][4];
#pragma unroll
    for (int m = 0; m < 2; ++m)
#pragma unroll
        for (int nf = 0; nf < 4; ++nf) acc[m][nf] = (f32x4){0.f, 0.f, 0.f, 0.f};

#define M2_MFMA6()                                                                               \
    for (int nf = 0; nf < 4; ++nf) {                                                             \
        for (int m = 0; m < 2; ++m) {                                                            \
            acc[m][nf] = __builtin_amdgcn_mfma_f32_16x16x32_bf16(a_h[m], b_h[nf], acc[m][nf], 0, 0, 0); \
            acc[m][nf] = __builtin_amdgcn_mfma_f32_16x16x32_bf16(a_m[m], b_h[nf], acc[m][nf], 0, 0, 0); \
            acc[m][nf] = __builtin_amdgcn_mfma_f32_16x16x32_bf16(a_h[m], b_m[nf], acc[m][nf], 0, 0, 0); \
            acc[m][nf] = __builtin_amdgcn_mfma_f32_16x16x32_bf16(a_l[m], b_h[nf], acc[m][nf], 0, 0, 0); \
            acc[m][nf] = __builtin_amdgcn_mfma_f32_16x16x32_bf16(a_m[m], b_m[nf], acc[m][nf], 0, 0, 0); \
            acc[m][nf] = __builtin_amdgcn_mfma_f32_16x16x32_bf16(a_h[m], b_l[nf], acc[m][nf], 0, 0, 0); \
        }                                                                                        \
    }

    for (int kt = 0; kt < 8; ++kt) {
        const int ka = kt * 32 + lk;
        short8 a_h[2], a_m[2], a_l[2];
        a_h[0] = *(const short8*)&Ah[lr * XSTR + ka];
        a_h[1] = *(const short8*)&Ah[(16 + lr) * XSTR + ka];
        a_m[0] = *(const short8*)&Am[lr * XSTR + ka];
        a_m[1] = *(const short8*)&Am[(16 + lr) * XSTR + ka];
        a_l[0] = *(const short8*)&Al[lr * XSTR + ka];
        a_l[1] = *(const short8*)&Al[(16 + lr) * XSTR + ka];
        short8 b_h[4], b_m[4], b_l[4];
#pragma unroll
        for (int nf = 0; nf < 4; ++nf) {
            const int off = fb[nf] + kt * 512;
            b_h[nf] = *(const short8*)&Bh[off];
            b_m[nf] = *(const short8*)&Bm[off];
            b_l[nf] = *(const short8*)&Bl[off];
        }
#pragma unroll
        M2_MFMA6()
    }
    { // kt = 8: u + pad
        short8 a_h[2], a_m[2], a_l[2];
        if (lg == 0) {
            float vv[8];
            const float4* up = (const float4*)&u[(size_t)(r0 + lr) * 8];
            float4 v0 = up[0], v1 = up[1];
            vv[0] = v0.x; vv[1] = v0.y; vv[2] = v0.z; vv[3] = v0.w;
            vv[4] = v1.x; vv[5] = v1.y; vv[6] = v1.z; vv[7] = v1.w;
            split8(vv, a_h[0], a_m[0], a_l[0]);
            const float4* up2 = (const float4*)&u[(size_t)(r0 + 16 + lr) * 8];
            float4 w0 = up2[0], w1 = up2[1];
            vv[0] = w0.x; vv[1] = w0.y; vv[2] = w0.z; vv[3] = w0.w;
            vv[4] = w1.x; vv[5] = w1.y; vv[6] = w1.z; vv[7] = w1.w;
            split8(vv, a_h[1], a_m[1], a_l[1]);
        } else {
            short8 z = {0, 0, 0, 0, 0, 0, 0, 0};
            a_h[0] = z; a_h[1] = z; a_m[0] = z; a_m[1] = z; a_l[0] = z; a_l[1] = z;
        }
        short8 b_h[4], b_m[4], b_l[4];
#pragma unroll
        for (int nf = 0; nf < 4; ++nf) {
            const int off = fb[nf] + 8 * 512;
            b_h[nf] = *(const short8*)&Bh[off];
            b_m[nf] = *(const short8*)&Bm[off];
            b_l[nf] = *(const short8*)&Bl[off];
        }
#pragma unroll
        M2_MFMA6()
    }
    for (int kt = 9; kt < 11; ++kt) { // w tiles (8-product)
        const int wc = (kt - 9) * 32 + lk;
        short8 a_h[2], a_m[2], a_l[2];
        {
            float vv[8];
            const float4* wp = (const float4*)&wg[(size_t)(r0 + lr) * 64 + wc];
            float4 v0 = wp[0], v1 = wp[1];
            vv[0] = v0.x; vv[1] = v0.y; vv[2] = v0.z; vv[3] = v0.w;
            vv[4] = v1.x; vv[5] = v1.y; vv[6] = v1.z; vv[7] = v1.w;
            split8(vv, a_h[0], a_m[0], a_l[0]);
            const float4* wp2 = (const float4*)&wg[(size_t)(r0 + 16 + lr) * 64 + wc];
            float4 w0 = wp2[0], w1 = wp2[1];
            vv[0] = w0.x; vv[1] = w0.y; vv[2] = w0.z; vv[3] = w0.w;
            vv[4] = w1.x; vv[5] = w1.y; vv[6] = w1.z; vv[7] = w1.w;
            split8(vv, a_h[1], a_m[1], a_l[1]);
        }
        short8 b_h[4], b_m[4], b_l[4];
#pragma unroll
        for (int nf = 0; nf < 4; ++nf) {
            const int off = fb[nf] + kt * 512;
            b_h[nf] = *(const short8*)&Bh[off];
            b_m[nf] = *(const short8*)&Bm[off];
            b_l[nf] = *(const short8*)&Bl[off];
        }
#pragma unroll
        for (int nf = 0; nf < 4; ++nf) {
#pragma unroll
            for (int m = 0; m < 2; ++m) {
                acc[m][nf] = __builtin_amdgcn_mfma_f32_16x16x32_bf16(a_h[m], b_h[nf], acc[m][nf], 0, 0, 0);
                acc[m][nf] = __builtin_amdgcn_mfma_f32_16x16x32_bf16(a_m[m], b_h[nf], acc[m][nf], 0, 0, 0);
                acc[m][nf] = __builtin_amdgcn_mfma_f32_16x16x32_bf16(a_h[m], b_m[nf], acc[m][nf], 0, 0, 0);
                acc[m][nf] = __builtin_amdgcn_mfma_f32_16x16x32_bf16(a_l[m], b_h[nf], acc[m][nf], 0, 0, 0);
                acc[m][nf] = __builtin_amdgcn_mfma_f32_16x16x32_bf16(a_m[m], b_m[nf], acc[m][nf], 0, 0, 0);
                acc[m][nf] = __builtin_amdgcn_mfma_f32_16x16x32_bf16(a_h[m], b_l[nf], acc[m][nf], 0, 0, 0);
                acc[m][nf] = __builtin_amdgcn_mfma_f32_16x16x32_bf16(a_m[m], b_l[nf], acc[m][nf], 0, 0, 0);
                acc[m][nf] = __builtin_amdgcn_mfma_f32_16x16x32_bf16(a_l[m], b_m[nf], acc[m][nf], 0, 0, 0);
            }
        }
    }
#pragma unroll
    for (int m = 0; m < 2; ++m)
#pragma unroll
        for (int nf = 0; nf < 4; ++nf)
#pragma unroll
            for (int j = 0; j < 4; ++j)
                out[(size_t)(r0 + m * 16 + lg * 4 + j) * 256 + n0 + nf * 16 + lr] = acc[m][nf][j];
}

extern "C" void kernel_launch(void* const* d_in, const int* in_sizes, int n_in,
                              void* d_out, int out_size, void* d_ws, size_t ws_size,
                              hipStream_t stream) {
    const float* x   = (const float*)d_in[0];
    const float* u   = (const float*)d_in[1];
    const float* Xm  = (const float*)d_in[2];
    const float* Um  = (const float*)d_in[3];
    const float* Y1  = (const float*)d_in[4];
    const float* XPm = (const float*)d_in[5];
    const float* B2  = (const float*)d_in[6];
    const float* D12 = (const float*)d_in[7];
    const float* bv  = (const float*)d_in[8];
    float* out = (float*)d_out;
    float* ws  = (float*)d_ws;

    float* H    = ws + WS_H;
    float* C0   = ws + WS_C;
    float* C1   = ws + WS_C2;
    float* Y    = ws + WS_Y;
    float* RHS  = ws + WS_RHS;
    float* D11g = ws + WS_D11;
    float* E0   = ws + WS_E0;
    float* E1   = ws + WS_E1;
    unsigned short* Bh  = (unsigned short*)(ws + WS_WFH);
    unsigned short* Bm  = (unsigned short*)(ws + WS_WFM);
    unsigned short* Bl  = (unsigned short*)(ws + WS_WFL);
    unsigned short* Bbh = (unsigned short*)(ws + WS_BBH);
    unsigned short* Bbm = (unsigned short*)(ws + WS_BBM);
    unsigned short* Bbl = (unsigned short*)(ws + WS_BBL);
    float* wg = ws + WS_WG;

    k_build<<<656, 256, 0, stream>>>(Xm, XPm, H, C0);
    k_derived<<<442, 256, 0, stream>>>(H, Um, Y1, B2, D12, Y, RHS, D11g,
                                       Bh, Bm, Bl, Bbh, Bbm, Bbl, C0, E0);
    k_basrec<<<2048, 256, 0, stream>>>(x, u, Bbh, Bbm, Bbl, bv, D11g, wg);
    k_gjS<<<16, 256, 0, stream>>>(C0, C1, E0, E1, 0, 1);
    k_gjS<<<16, 256, 0, stream>>>(C1, C0, E1, E0, 1, 2);
    k_gjS<<<16, 256, 0, stream>>>(C0, C1, E0, E1, 2, 3);
    k_gjS<<<16, 256, 0, stream>>>(C1, C0, E1, E0, 3, -1);
    k_apply2<<<20, 256, 0, stream>>>(C0, Y, RHS, Bh, Bm, Bl);
    k_m2<<<2048, 256, 0, stream>>>(x, wg, u, Bh, Bm, Bl, out);
}

// Round 17
// 337.869 us; speedup vs baseline: 1.0744x; 1.0744x over previous
//
#include <hip/hip_runtime.h>

#define EPS_C 0.01f

typedef __attribute__((ext_vector_type(8))) short short8;
typedef __attribute__((ext_vector_type(4))) float f32x4;
typedef __attribute__((ext_vector_type(4))) unsigned short u16x4;
typedef __attribute__((ext_vector_type(8))) unsigned short u16x8;

// ---------- workspace layout (float offsets) ----------
#define WS_H    0        // 320*320
#define WS_C    102400   // 256*256  C0
#define WS_C2   167936   // 256*256  C1
#define WS_Y    233472   // 256*256
#define WS_RHS  299008   // 256*64
#define WS_D11  331776   // 64*64
#define WS_WFH  419840   // 256*352 u16 each, fragment-packed
#define WS_WFM  464896
#define WS_WFL  509952
#define WS_BBH  555008   // 64*288 u16 each, fragment-packed
#define WS_BBM  564224
#define WS_BBL  573440
#define WS_WG   582656   // 65536*64 fp32
#define WS_E0   4776960  // 64*64 fp32
#define WS_E1   4781056  // 64*64 fp32

__device__ __forceinline__ int wfoff(int n, int k) {
    return (((n >> 4) * 44 + (k >> 5) * 4 + ((k >> 3) & 3)) << 7) + ((n & 15) << 3) + (k & 7);
}
__device__ __forceinline__ int bboff(int n, int k) {
    return (((n >> 4) * 36 + (k >> 5) * 4 + ((k >> 3) & 3)) << 7) + ((n & 15) << 3) + (k & 7);
}

__device__ __forceinline__ unsigned short f2bf(float f) {
    unsigned int u = __float_as_uint(f);
    unsigned int r = (u + 0x7fffu + ((u >> 16) & 1u)) >> 16;
    return (unsigned short)r;
}
__device__ __forceinline__ float bf2f(unsigned short h) {
    return __uint_as_float(((unsigned int)h) << 16);
}
__device__ __forceinline__ void split1(float f, unsigned short& h, unsigned short& m, unsigned short& l) {
    h = f2bf(f);
    float r1 = f - bf2f(h);
    m = f2bf(r1);
    l = f2bf(r1 - bf2f(m));
}
__device__ __forceinline__ void split8(const float* v, short8& h8, short8& m8, short8& l8) {
#pragma unroll
    for (int j = 0; j < 8; ++j) {
        unsigned short h, m, l;
        split1(v[j], h, m, l);
        h8[j] = (short)h; m8[j] = (short)m; l8[j] = (short)l;
    }
}

// ---------------- setup: P and H builds ----------------
__global__ void k_build(const float* __restrict__ Xm, const float* __restrict__ XPm,
                        float* __restrict__ H, float* __restrict__ P) {
    int idx = blockIdx.x * 256 + threadIdx.x;
    if (idx < 102400) {
        int i = idx / 320, j = idx - i * 320;
        const float4* a = (const float4*)(Xm + i * 320);
        const float4* b = (const float4*)(Xm + j * 320);
        float s = 0.f;
        for (int k = 0; k < 80; ++k) {
            float4 va = a[k], vb = b[k];
            s += va.x * vb.x + va.y * vb.y + va.z * vb.z + va.w * vb.w;
        }
        H[idx] = (i == j) ? s + EPS_C : s;
    } else {
        idx -= 102400;
        if (idx < 65536) {
            int i = idx >> 8, j = idx & 255;
            const float4* a = (const float4*)(XPm + i * 256);
            const float4* b = (const float4*)(XPm + j * 256);
            float s = 0.f;
            for (int k = 0; k < 64; ++k) {
                float4 va = a[k], vb = b[k];
                s += va.x * vb.x + va.y * vb.y + va.z * vb.z + va.w * vb.w;
            }
            P[idx] = (i == j) ? s + EPS_C : s;
        }
    }
}

// ---------------- derived + packs + first inv8 (block 441) ----------------
__global__ void __launch_bounds__(256) k_derived(const float* __restrict__ H, const float* __restrict__ Um,
                          const float* __restrict__ Y1, const float* __restrict__ B2,
                          const float* __restrict__ D12,
                          float* __restrict__ Y, float* __restrict__ RHS,
                          float* __restrict__ D11g,
                          unsigned short* __restrict__ Bh, unsigned short* __restrict__ Bm,
                          unsigned short* __restrict__ Bl,
                          unsigned short* __restrict__ Bbh, unsigned short* __restrict__ Bbm,
                          unsigned short* __restrict__ Bbl,
                          const float* __restrict__ C0, float* __restrict__ E0) {
    __shared__ __align__(16) float M[64 * 68];
    __shared__ __align__(16) float Rs[8 * 68];
    __shared__ __align__(16) float Ts[64 * 8];
    __shared__ float E8s[8 * 9];
    const int tid = threadIdx.x;
    if (blockIdx.x == 441) { // inv8 of C0 block (0,0) -> E0
        const int ti = tid & 15, tj = tid >> 4;
#pragma unroll
        for (int t = 0; t < 4; ++t) {
            int e = tid + t * 256;
            int r = e >> 4, c4 = e & 15;
            float4 v = *(const float4*)&C0[(size_t)r * 256 + c4 * 4];
            *(float4*)&M[r * 68 + c4 * 4] = v;
        }
        __syncthreads();
        for (int s = 0; s < 8; ++s) {
            if (tid < 64) {
                const int lane = tid;
                float e8[8];
#pragma unroll
                for (int j = 0; j < 8; ++j) e8[j] = 0.f;
                if (lane < 8) {
#pragma unroll
                    for (int j = 0; j < 8; ++j) e8[j] = M[(s * 8 + lane) * 68 + s * 8 + j];
                }
#pragma unroll
                for (int k = 0; k < 8; ++k) {
                    const float p = __shfl(e8[k], k);
                    const float rinv = 1.0f / p;
                    const float f = -e8[k] * rinv;
                    const bool isk = (lane == k);
#pragma unroll
                    for (int j = 0; j < 8; ++j) {
                        const float prj = __shfl(e8[j], k);
                        if (j == k) e8[j] = isk ? rinv : f;
                        else        e8[j] = isk ? prj * rinv : fmaf(f, prj, e8[j]);
                    }
                }
                if (lane < 8) {
#pragma unroll
                    for (int j = 0; j < 8; ++j) E8s[lane * 9 + j] = e8[j];
                }
            }
            __syncthreads();
#pragma unroll
            for (int t = 0; t < 2; ++t) {
                int e = tid + t * 256;
                int r = e >> 6, c = e & 63;
                Rs[r * 68 + c] = M[(s * 8 + r) * 68 + c];
            }
#pragma unroll
            for (int t = 0; t < 2; ++t) {
                int e = tid + t * 256;
                int i = e >> 3, c = e & 7;
                float acc = 0.f;
#pragma unroll
                for (int j = 0; j < 8; ++j) acc = fmaf(M[i * 68 + s * 8 + j], E8s[j * 9 + c], acc);
                Ts[i * 8 + c] = acc;
            }
            __syncthreads();
            {
                const bool rowIn = ((ti >> 1) == s);
                const bool colIn = ((tj >> 1) == s);
                const int i0 = ti * 4, j0 = tj * 4;
                float nv[4][4];
                if (rowIn && colIn) {
#pragma unroll
                    for (int r = 0; r < 4; ++r)
#pragma unroll
                        for (int d = 0; d < 4; ++d)
                            nv[r][d] = E8s[(i0 - s * 8 + r) * 9 + (j0 - s * 8 + d)];
                } else if (rowIn) {
#pragma unroll
                    for (int r = 0; r < 4; ++r)
#pragma unroll
                        for (int d = 0; d < 4; ++d) {
                            float acc = 0.f;
#pragma unroll
                            for (int c = 0; c < 8; ++c)
                                acc = fmaf(E8s[(i0 - s * 8 + r) * 9 + c], Rs[c * 68 + j0 + d], acc);
                            nv[r][d] = acc;
                        }
                } else if (colIn) {
#pragma unroll
                    for (int r = 0; r < 4; ++r)
#pragma unroll
                        for (int d = 0; d < 4; ++d)
                            nv[r][d] = -Ts[(i0 + r) * 8 + (j0 - s * 8 + d)];
                } else {
#pragma unroll
                    for (int r = 0; r < 4; ++r)
#pragma unroll
                        for (int d = 0; d < 4; ++d) {
                            float acc = M[(i0 + r) * 68 + j0 + d];
#pragma unroll
                            for (int c = 0; c < 8; ++c)
                                acc = fmaf(-Ts[(i0 + r) * 8 + c], Rs[c * 68 + j0 + d], acc);
                            nv[r][d] = acc;
                        }
                }
#pragma unroll
                for (int r = 0; r < 4; ++r)
#pragma unroll
                    for (int d = 0; d < 4; ++d) M[(i0 + r) * 68 + j0 + d] = nv[r][d];
            }
            __syncthreads();
        }
#pragma unroll
        for (int t = 0; t < 4; ++t) {
            int e = tid + t * 256;
            int r = e >> 4, c4 = e & 15;
            float4 v = *(const float4*)&M[r * 68 + c4 * 4];
            *(float4*)&E0[(size_t)r * 64 + c4 * 4] = v;
        }
        return;
    }
    int idx = blockIdx.x * 256 + tid;
    if (idx < 65536) {
        int i = idx >> 8, j = idx & 255;
        Y[idx] = -0.5f * (H[i * 320 + j] + Y1[i * 256 + j] - Y1[j * 256 + i]);
        return;
    }
    idx -= 65536;
    if (idx < 16384) {
        RHS[idx] = -H[(idx >> 6) * 320 + 256 + (idx & 63)] - Um[idx];
        return;
    }
    idx -= 16384;
    if (idx < 4096) {
        int q = idx >> 6, j = idx & 63;
        float lam = 0.5f * H[(256 + q) * 320 + 256 + q];
        D11g[idx] = (j < q) ? -H[(256 + q) * 320 + 256 + j] / lam : 0.f;
        return;
    }
    idx -= 4096;
    if (idx < 8192) {
        int o = idx >> 5, cc = idx & 31;
        float f = (cc < 8) ? B2[o * 8 + cc] : 0.f;
        unsigned short h, m, l;
        split1(f, h, m, l);
        int off = wfoff(o, 256 + cc);
        Bh[off] = h; Bm[off] = m; Bl[off] = l;
        return;
    }
    idx -= 8192;
    if (idx < 18432) {
        int q = idx / 288, k = idx - q * 288;
        float f;
        if (k < 256) {
            float lam = 0.5f * H[(256 + q) * 320 + 256 + q];
            f = Um[(size_t)k * 64 + q] / lam;
        } else if (k < 264) f = D12[(size_t)q * 8 + (k - 256)];
        else f = 0.f;
        unsigned short h, m, l;
        split1(f, h, m, l);
        int off = bboff(q, k);
        Bbh[off] = h; Bbm[off] = m; Bbl[off] = l;
    }
}

// ---------------- GJ sweep + embedded inverse of next diag block (E double-buffered) --------
__global__ void __launch_bounds__(256) k_gjS(const float* __restrict__ Cold, float* __restrict__ Cnew,
                                             const float* __restrict__ E, float* __restrict__ Eout,
                                             int b, int nb) {
    const int I = blockIdx.x >> 2, J = blockIdx.x & 3;
    const int tid = threadIdx.x;
    const int ti = tid & 15, tj = tid >> 4;
    if (I == b && J == b) { // diag <- E
        const int r = tid >> 2, seg = tid & 3;
#pragma unroll
        for (int t = 0; t < 4; ++t) {
            float4 v = *(const float4*)&E[(size_t)r * 64 + seg * 16 + t * 4];
            *(float4*)&Cnew[(size_t)(b * 64 + r) * 256 + b * 64 + seg * 16 + t * 4] = v;
        }
        return;
    }
    __shared__ __align__(16) float Es[64 * 68];
    __shared__ __align__(16) float S1[64 * 68];
    __shared__ __align__(16) float S2[64 * 68];
    for (int e = tid; e < 1024; e += 256) {
        int r = e >> 4, c4 = e & 15;
        float4 v = *(const float4*)&E[(size_t)r * 64 + c4 * 4];
        *(float4*)&Es[r * 68 + c4 * 4] = v;
    }
    if (I == b) { // row block: W = E * Cold[b,J]
        for (int e = tid; e < 1024; e += 256) {
            int r = e >> 4, c4 = e & 15;
            float4 v = *(const float4*)&Cold[(size_t)(b * 64 + r) * 256 + J * 64 + c4 * 4];
            *(float4*)&S1[r * 68 + c4 * 4] = v;
        }
        __syncthreads();
        float acc[4][4];
#pragma unroll
        for (int r = 0; r < 4; ++r)
#pragma unroll
            for (int d = 0; d < 4; ++d) acc[r][d] = 0.f;
        for (int mm = 0; mm < 64; ++mm) {
            float a4[4], b4[4];
#pragma unroll
            for (int d = 0; d < 4; ++d) { a4[d] = Es[(ti * 4 + d) * 68 + mm]; b4[d] = S1[mm * 68 + tj * 4 + d]; }
#pragma unroll
            for (int r = 0; r < 4; ++r)
#pragma unroll
                for (int d = 0; d < 4; ++d) acc[r][d] = fmaf(a4[r], b4[d], acc[r][d]);
        }
#pragma unroll
        for (int r = 0; r < 4; ++r) {
            float4 v = {acc[r][0], acc[r][1], acc[r][2], acc[r][3]};
            *(float4*)&Cnew[(size_t)(b * 64 + ti * 4 + r) * 256 + J * 64 + tj * 4] = v;
        }
        return;
    }
    if (J == b) { // col block: -Cold[I,b] * E
        for (int e = tid; e < 1024; e += 256) {
            int r = e >> 4, c4 = e & 15;
            float4 v = *(const float4*)&Cold[(size_t)(I * 64 + r) * 256 + b * 64 + c4 * 4];
            *(float4*)&S1[r * 68 + c4 * 4] = v;
        }
        __syncthreads();
        float acc[4][4];
#pragma unroll
        for (int r = 0; r < 4; ++r)
#pragma unroll
            for (int d = 0; d < 4; ++d) acc[r][d] = 0.f;
        for (int kk = 0; kk < 64; ++kk) {
            float a4[4], b4[4];
#pragma unroll
            for (int d = 0; d < 4; ++d) { a4[d] = S1[(ti * 4 + d) * 68 + kk]; b4[d] = Es[kk * 68 + tj * 4 + d]; }
#pragma unroll
            for (int r = 0; r < 4; ++r)
#pragma unroll
                for (int d = 0; d < 4; ++d) acc[r][d] = fmaf(a4[r], b4[d], acc[r][d]);
        }
#pragma unroll
        for (int r = 0; r < 4; ++r) {
            float4 v = {-acc[r][0], -acc[r][1], -acc[r][2], -acc[r][3]};
            *(float4*)&Cnew[(size_t)(I * 64 + ti * 4 + r) * 256 + b * 64 + tj * 4] = v;
        }
        return;
    }
    // update tile
    for (int e = tid; e < 1024; e += 256) {
        int r = e >> 4, c4 = e & 15;
        float4 v = *(const float4*)&Cold[(size_t)(I * 64 + r) * 256 + b * 64 + c4 * 4];
        *(float4*)&S1[r * 68 + c4 * 4] = v;
        float4 w = *(const float4*)&Cold[(size_t)(b * 64 + r) * 256 + J * 64 + c4 * 4];
        *(float4*)&S2[r * 68 + c4 * 4] = w;
    }
    __syncthreads();
    float t4[4][4];
#pragma unroll
    for (int r = 0; r < 4; ++r)
#pragma unroll
        for (int d = 0; d < 4; ++d) t4[r][d] = 0.f;
    for (int kk = 0; kk < 64; ++kk) {
        float a4[4], b4[4];
#pragma unroll
        for (int d = 0; d < 4; ++d) { a4[d] = S1[(ti * 4 + d) * 68 + kk]; b4[d] = Es[kk * 68 + tj * 4 + d]; }
#pragma unroll
        for (int r = 0; r < 4; ++r)
#pragma unroll
            for (int d = 0; d < 4; ++d) t4[r][d] = fmaf(a4[r], b4[d], t4[r][d]);
    }
    __syncthreads();
#pragma unroll
    for (int r = 0; r < 4; ++r)
#pragma unroll
        for (int d = 0; d < 4; ++d) S1[(ti * 4 + r) * 68 + tj * 4 + d] = t4[r][d];
    __syncthreads();
    float acc[4][4];
#pragma unroll
    for (int r = 0; r < 4; ++r) {
        float4 cv = *(const float4*)&Cold[(size_t)(I * 64 + ti * 4 + r) * 256 + J * 64 + tj * 4];
        acc[r][0] = cv.x; acc[r][1] = cv.y; acc[r][2] = cv.z; acc[r][3] = cv.w;
    }
    for (int kk = 0; kk < 64; ++kk) {
        float a4[4], b4[4];
#pragma unroll
        for (int d = 0; d < 4; ++d) { a4[d] = S1[(ti * 4 + d) * 68 + kk]; b4[d] = S2[kk * 68 + tj * 4 + d]; }
#pragma unroll
        for (int r = 0; r < 4; ++r)
#pragma unroll
            for (int d = 0; d < 4; ++d) acc[r][d] = fmaf(-a4[r], b4[d], acc[r][d]);
    }
#pragma unroll
    for (int r = 0; r < 4; ++r) {
        float4 v = {acc[r][0], acc[r][1], acc[r][2], acc[r][3]};
        *(float4*)&Cnew[(size_t)(I * 64 + ti * 4 + r) * 256 + J * 64 + tj * 4] = v;
    }
    // embedded inverse of next sweep's diag block -> Eout
    if (I == nb && J == nb) {
        float* M   = Es;
        float* Rs2 = S2;
        float* Ts2 = S2 + 1024;
        float* E8s = S2 + 1664;
        __syncthreads();
#pragma unroll
        for (int r = 0; r < 4; ++r)
#pragma unroll
            for (int d = 0; d < 4; ++d)
                M[(ti * 4 + r) * 68 + tj * 4 + d] = acc[r][d];
        __syncthreads();
        for (int s = 0; s < 8; ++s) {
            if (tid < 64) {
                const int lane = tid;
                float e8[8];
#pragma unroll
                for (int j = 0; j < 8; ++j) e8[j] = 0.f;
                if (lane < 8) {
#pragma unroll
                    for (int j = 0; j < 8; ++j) e8[j] = M[(s * 8 + lane) * 68 + s * 8 + j];
                }
#pragma unroll
                for (int k = 0; k < 8; ++k) {
                    const float p = __shfl(e8[k], k);
                    const float rinv = 1.0f / p;
                    const float f = -e8[k] * rinv;
                    const bool isk = (lane == k);
#pragma unroll
                    for (int j = 0; j < 8; ++j) {
                        const float prj = __shfl(e8[j], k);
                        if (j == k) e8[j] = isk ? rinv : f;
                        else        e8[j] = isk ? prj * rinv : fmaf(f, prj, e8[j]);
                    }
                }
                if (lane < 8) {
#pragma unroll
                    for (int j = 0; j < 8; ++j) E8s[lane * 9 + j] = e8[j];
                }
            }
            __syncthreads();
#pragma unroll
            for (int t = 0; t < 2; ++t) {
                int e = tid + t * 256;
                int r = e >> 6, c = e & 63;
                Rs2[r * 68 + c] = M[(s * 8 + r) * 68 + c];
            }
#pragma unroll
            for (int t = 0; t < 2; ++t) {
                int e = tid + t * 256;
                int i = e >> 3, c = e & 7;
                float a2 = 0.f;
#pragma unroll
                for (int j = 0; j < 8; ++j) a2 = fmaf(M[i * 68 + s * 8 + j], E8s[j * 9 + c], a2);
                Ts2[i * 8 + c] = a2;
            }
            __syncthreads();
            {
                const bool rowIn = ((ti >> 1) == s);
                const bool colIn = ((tj >> 1) == s);
                const int i0 = ti * 4, j0 = tj * 4;
                float nv[4][4];
                if (rowIn && colIn) {
#pragma unroll
                    for (int r = 0; r < 4; ++r)
#pragma unroll
                        for (int d = 0; d < 4; ++d)
                            nv[r][d] = E8s[(i0 - s * 8 + r) * 9 + (j0 - s * 8 + d)];
                } else if (rowIn) {
#pragma unroll
                    for (int r = 0; r < 4; ++r)
#pragma unroll
                        for (int d = 0; d < 4; ++d) {
                            float a2 = 0.f;
#pragma unroll
                            for (int c = 0; c < 8; ++c)
                                a2 = fmaf(E8s[(i0 - s * 8 + r) * 9 + c], Rs2[c * 68 + j0 + d], a2);
                            nv[r][d] = a2;
                        }
                } else if (colIn) {
#pragma unroll
                    for (int r = 0; r < 4; ++r)
#pragma unroll
                        for (int d = 0; d < 4; ++d)
                            nv[r][d] = -Ts2[(i0 + r) * 8 + (j0 - s * 8 + d)];
                } else {
#pragma unroll
                    for (int r = 0; r < 4; ++r)
#pragma unroll
                        for (int d = 0; d < 4; ++d) {
                            float a2 = M[(i0 + r) * 68 + j0 + d];
#pragma unroll
                            for (int c = 0; c < 8; ++c)
                                a2 = fmaf(-Ts2[(i0 + r) * 8 + c], Rs2[c * 68 + j0 + d], a2);
                            nv[r][d] = a2;
                        }
                }
#pragma unroll
                for (int r = 0; r < 4; ++r)
#pragma unroll
                    for (int d = 0; d < 4; ++d) M[(i0 + r) * 68 + j0 + d] = nv[r][d];
            }
            __syncthreads();
        }
#pragma unroll
        for (int t = 0; t < 4; ++t) {
            int e = tid + t * 256;
            int r = e >> 4, c4 = e & 15;
            float4 v = *(const float4*)&M[r * 68 + c4 * 4];
            *(float4*)&Eout[(size_t)r * 64 + c4 * 4] = v;
        }
    }
}

// ---------------- apply: Wf cols = Pinv @ [Y | RHS], fragment-packed 3-way ----------------
__global__ void __launch_bounds__(256) k_apply2(const float* __restrict__ PI, const float* __restrict__ Y,
                                                const float* __restrict__ RHS,
                                                unsigned short* __restrict__ Bh, unsigned short* __restrict__ Bm,
                                                unsigned short* __restrict__ Bl) {
    const int i0 = ((int)blockIdx.x / 5) * 64;
    const int c0 = ((int)blockIdx.x % 5) * 64;
    __shared__ __align__(16) float S1[64 * 68], S2[64 * 68];
    const int tid = threadIdx.x;
    const int ti = tid & 15, tj = tid >> 4;
    float acc[4][4];
#pragma unroll
    for (int r = 0; r < 4; ++r)
#pragma unroll
        for (int d = 0; d < 4; ++d) acc[r][d] = 0.f;
    for (int kc = 0; kc < 4; ++kc) {
        __syncthreads();
        for (int e = tid; e < 1024; e += 256) {
            int i = e >> 4, k4 = e & 15;
            float4 v = *(const float4*)&PI[(size_t)(i0 + i) * 256 + kc * 64 + k4 * 4];
            S1[(k4 * 4 + 0) * 68 + i] = v.x;
            S1[(k4 * 4 + 1) * 68 + i] = v.y;
            S1[(k4 * 4 + 2) * 68 + i] = v.z;
            S1[(k4 * 4 + 3) * 68 + i] = v.w;
            float4 w;
            if (c0 < 256) w = *(const float4*)&Y[(size_t)(kc * 64 + i) * 256 + c0 + k4 * 4];
            else          w = *(const float4*)&RHS[(size_t)(kc * 64 + i) * 64 + k4 * 4];
            *(float4*)&S2[i * 68 + k4 * 4] = w;
        }
        __syncthreads();
        for (int kk = 0; kk < 64; ++kk) {
            float4 pv = *(const float4*)&S1[kk * 68 + ti * 4];
            float4 gv = *(const float4*)&S2[kk * 68 + tj * 4];
            float p4[4] = {pv.x, pv.y, pv.z, pv.w};
            float g4[4] = {gv.x, gv.y, gv.z, gv.w};
#pragma unroll
            for (int r = 0; r < 4; ++r)
#pragma unroll
                for (int d = 0; d < 4; ++d) acc[r][d] = fmaf(p4[r], g4[d], acc[r][d]);
        }
    }
    const int pc0 = (c0 < 256) ? c0 : 288;
#pragma unroll
    for (int r = 0; r < 4; ++r)
#pragma unroll
        for (int d = 0; d < 4; ++d) {
            unsigned short h, m, l;
            split1(acc[r][d], h, m, l);
            int off = wfoff(i0 + ti * 4 + r, pc0 + tj * 4 + d);
            Bh[off] = h; Bm[off] = m; Bl[off] = l;
        }
}

// ---------------- main 1a: base = [x|u|0] @ Bb^T + bv (packed-fragment B, 3 blk/CU) --------
#define XSTR 264
__global__ void __launch_bounds__(256, 3) k_base(const float* __restrict__ x, const float* __restrict__ u,
                                                 const unsigned short* __restrict__ Bbh,
                                                 const unsigned short* __restrict__ Bbm,
                                                 const unsigned short* __restrict__ Bbl,
                                                 const float* __restrict__ bv,
                                                 float* __restrict__ wg) {
    __shared__ __align__(16) unsigned short Ah[32 * XSTR];
    __shared__ __align__(16) unsigned short Am[32 * XSTR];
    __shared__ __align__(16) unsigned short Al[32 * XSTR];
    const int tid = threadIdx.x;
    const int r0 = blockIdx.x * 32;
    {
        const float4* xg4 = (const float4*)(x + (size_t)r0 * 256);
#pragma unroll
        for (int i = 0; i < 8; ++i) {
            int e = tid + i * 256, r = e >> 6, c4 = e & 63;
            float4 v = xg4[e];
            float vv[4] = {v.x, v.y, v.z, v.w};
            u16x4 hv, mv, lv;
#pragma unroll
            for (int j = 0; j < 4; ++j) {
                unsigned short h, m, l;
                split1(vv[j], h, m, l);
                hv[j] = h; mv[j] = m; lv[j] = l;
            }
            *(u16x4*)&Ah[r * XSTR + c4 * 4] = hv;
            *(u16x4*)&Am[r * XSTR + c4 * 4] = mv;
            *(u16x4*)&Al[r * XSTR + c4 * 4] = lv;
        }
    }
    __syncthreads();
    const int lane = tid & 63, wid = tid >> 6;
    const int n0 = wid * 16;
    const int lr = lane & 15, lg = lane >> 4;
    const int lk = lg * 8;
    const int fb = wid * 4608 + lg * 128 + lr * 8;
    f32x4 acc[2];
    acc[0] = (f32x4){0.f, 0.f, 0.f, 0.f};
    acc[1] = (f32x4){0.f, 0.f, 0.f, 0.f};
    for (int kt = 0; kt < 9; ++kt) {
        const int ka = kt * 32 + lk;
        short8 a_h[2], a_m[2], a_l[2];
        if (kt < 8) {
            a_h[0] = *(const short8*)&Ah[lr * XSTR + ka];
            a_h[1] = *(const short8*)&Ah[(16 + lr) * XSTR + ka];
            a_m[0] = *(const short8*)&Am[lr * XSTR + ka];
            a_m[1] = *(const short8*)&Am[(16 + lr) * XSTR + ka];
            a_l[0] = *(const short8*)&Al[lr * XSTR + ka];
            a_l[1] = *(const short8*)&Al[(16 + lr) * XSTR + ka];
        } else {
            if (lg == 0) {
                float vv[8];
                const float4* up = (const float4*)&u[(size_t)(r0 + lr) * 8];
                float4 v0 = up[0], v1 = up[1];
                vv[0] = v0.x; vv[1] = v0.y; vv[2] = v0.z; vv[3] = v0.w;
                vv[4] = v1.x; vv[5] = v1.y; vv[6] = v1.z; vv[7] = v1.w;
                split8(vv, a_h[0], a_m[0], a_l[0]);
                const float4* up2 = (const float4*)&u[(size_t)(r0 + 16 + lr) * 8];
                float4 w0 = up2[0], w1 = up2[1];
                vv[0] = w0.x; vv[1] = w0.y; vv[2] = w0.z; vv[3] = w0.w;
                vv[4] = w1.x; vv[5] = w1.y; vv[6] = w1.z; vv[7] = w1.w;
                split8(vv, a_h[1], a_m[1], a_l[1]);
            } else {
                short8 z = {0, 0, 0, 0, 0, 0, 0, 0};
                a_h[0] = z; a_h[1] = z; a_m[0] = z; a_m[1] = z; a_l[0] = z; a_l[1] = z;
            }
        }
        const int off = fb + kt * 512;
        short8 b_h = *(const short8*)&Bbh[off];
        short8 b_m = *(const short8*)&Bbm[off];
        short8 b_l = *(const short8*)&Bbl[off];
#pragma unroll
        for (int m = 0; m < 2; ++m) {
            acc[m] = __builtin_amdgcn_mfma_f32_16x16x32_bf16(a_h[m], b_h, acc[m], 0, 0, 0);
            acc[m] = __builtin_amdgcn_mfma_f32_16x16x32_bf16(a_m[m], b_h, acc[m], 0, 0, 0);
            acc[m] = __builtin_amdgcn_mfma_f32_16x16x32_bf16(a_h[m], b_m, acc[m], 0, 0, 0);
            acc[m] = __builtin_amdgcn_mfma_f32_16x16x32_bf16(a_l[m], b_h, acc[m], 0, 0, 0);
            acc[m] = __builtin_amdgcn_mfma_f32_16x16x32_bf16(a_m[m], b_m, acc[m], 0, 0, 0);
            acc[m] = __builtin_amdgcn_mfma_f32_16x16x32_bf16(a_h[m], b_l, acc[m], 0, 0, 0);
        }
    }
    const float bvv = bv[n0 + lr];
#pragma unroll
    for (int m = 0; m < 2; ++m)
#pragma unroll
        for (int j = 0; j < 4; ++j)
            wg[(size_t)(r0 + m * 16 + lg * 4 + j) * 64 + n0 + lr] = acc[m][j] + bvv;
}

// ---------------- main 1b: per-row recurrence (in place on wg) ----------------
__global__ void __launch_bounds__(256) k_rec(float* __restrict__ wg, const float* __restrict__ D11g) {
    __shared__ float D[64 * 64];
    const int tid = threadIdx.x;
#pragma unroll
    for (int t = 0; t < 16; ++t) D[tid + t * 256] = D11g[tid + t * 256];
    __syncthreads();
    const size_t r = (size_t)blockIdx.x * 256 + tid;
    float w[64];
    float* wr = wg + r * 64;
#pragma unroll
    for (int c = 0; c < 16; ++c) {
        float4 v = *(const float4*)&wr[c * 4];
        w[4 * c] = v.x; w[4 * c + 1] = v.y; w[4 * c + 2] = v.z; w[4 * c + 3] = v.w;
    }
    w[0] = fmaxf(w[0], 0.f);
#pragma unroll
    for (int i = 1; i < 64; ++i) {
        float s0 = w[i], s1 = 0.f, s2 = 0.f, s3 = 0.f;
#pragma unroll
        for (int j = 0; j + 3 < i; j += 4) {
            s0 = fmaf(w[j + 0], D[i * 64 + j + 0], s0);
            s1 = fmaf(w[j + 1], D[i * 64 + j + 1], s1);
            s2 = fmaf(w[j + 2], D[i * 64 + j + 2], s2);
            s3 = fmaf(w[j + 3], D[i * 64 + j + 3], s3);
        }
#pragma unroll
        for (int j = i & ~3; j < i; ++j) s0 = fmaf(w[j], D[i * 64 + j], s0);
        w[i] = fmaxf((s0 + s1) + (s2 + s3), 0.f);
    }
#pragma unroll
    for (int c = 0; c < 16; ++c) {
        float4 v = {w[4 * c], w[4 * c + 1], w[4 * c + 2], w[4 * c + 3]};
        *(float4*)&wr[c * 4] = v;
    }
}

// ---------------- main 2: out = [x|u|0|w] @ Wf^T (packed-fragment B) ----------------
__global__ void __launch_bounds__(256, 3) k_m2(const float* __restrict__ x, const float* __restrict__ wg,
                                               const float* __restrict__ u,
                                               const unsigned short* __restrict__ Bh,
                                               const unsigned short* __restrict__ Bm,
                                               const unsigned short* __restrict__ Bl,
                                               float* __restrict__ out) {
    __shared__ __align__(16) unsigned short Ah[32 * XSTR];
    __shared__ __align__(16) unsigned short Am[32 * XSTR];
    __shared__ __align__(16) unsigned short Al[32 * XSTR];
    const int tid = threadIdx.x;
    const int r0 = blockIdx.x * 32;
    {
        const float4* xg4 = (const float4*)(x + (size_t)r0 * 256);
#pragma unroll
        for (int i = 0; i < 8; ++i) {
            int e = tid + i * 256, r = e >> 6, c4 = e & 63;
            float4 v = xg4[e];
            float vv[4] = {v.x, v.y, v.z, v.w};
            u16x4 hv, mv, lv;
#pragma unroll
            for (int j = 0; j < 4; ++j) {
                unsigned short h, m, l;
                split1(vv[j], h, m, l);
                hv[j] = h; mv[j] = m; lv[j] = l;
            }
            *(u16x4*)&Ah[r * XSTR + c4 * 4] = hv;
            *(u16x4*)&Am[r * XSTR + c4 * 4] = mv;
            *(u16x4*)&Al[r * XSTR + c4 * 4] = lv;
        }
    }
    __syncthreads();
    const int lane = tid & 63, wid = tid >> 6;
    const int n0 = wid * 64;
    const int lr = lane & 15, lg = lane >> 4;
    const int lk = lg * 8;
    const int lgoff = lg * 128 + lr * 8;
    int fb[4];
#pragma unroll
    for (int nf = 0; nf < 4; ++nf) fb[nf] = (wid * 4 + nf) * 5632 + lgoff;
    f32x4 acc[2][4];
#pragma unroll
    for (int m = 0; m < 2; ++m)
#pragma unroll
        for (int nf = 0; nf < 4; ++nf) acc[m][nf] = (f32x4){0.f, 0.f, 0.f, 0.f};

#define M2_MFMA6()                                                                               \
    for (int nf = 0; nf < 4; ++nf) {                                                             \
        for (int m = 0; m < 2; ++m) {                                                            \
            acc[m][nf] = __builtin_amdgcn_mfma_f32_16x16x32_bf16(a_h[m], b_h[nf], acc[m][nf], 0, 0, 0); \
            acc[m][nf] = __builtin_amdgcn_mfma_f32_16x16x32_bf16(a_m[m], b_h[nf], acc[m][nf], 0, 0, 0); \
            acc[m][nf] = __builtin_amdgcn_mfma_f32_16x16x32_bf16(a_h[m], b_m[nf], acc[m][nf], 0, 0, 0); \
            acc[m][nf] = __builtin_amdgcn_mfma_f32_16x16x32_bf16(a_l[m], b_h[nf], acc[m][nf], 0, 0, 0); \
            acc[m][nf] = __builtin_amdgcn_mfma_f32_16x16x32_bf16(a_m[m], b_m[nf], acc[m][nf], 0, 0, 0); \
            acc[m][nf] = __builtin_amdgcn_mfma_f32_16x16x32_bf16(a_h[m], b_l[nf], acc[m][nf], 0, 0, 0); \
        }                                                                                        \
    }

    for (int kt = 0; kt < 8; ++kt) {
        const int ka = kt * 32 + lk;
        short8 a_h[2], a_m[2], a_l[2];
        a_h[0] = *(const short8*)&Ah[lr * XSTR + ka];
        a_h[1] = *(const short8*)&Ah[(16 + lr) * XSTR + ka];
        a_m[0] = *(const short8*)&Am[lr * XSTR + ka];
        a_m[1] = *(const short8*)&Am[(16 + lr) * XSTR + ka];
        a_l[0] = *(const short8*)&Al[lr * XSTR + ka];
        a_l[1] = *(const short8*)&Al[(16 + lr) * XSTR + ka];
        short8 b_h[4], b_m[4], b_l[4];
#pragma unroll
        for (int nf = 0; nf < 4; ++nf) {
            const int off = fb[nf] + kt * 512;
            b_h[nf] = *(const short8*)&Bh[off];
            b_m[nf] = *(const short8*)&Bm[off];
            b_l[nf] = *(const short8*)&Bl[off];
        }
#pragma unroll
        M2_MFMA6()
    }
    { // kt = 8: u + pad
        short8 a_h[2], a_m[2], a_l[2];
        if (lg == 0) {
            float vv[8];
            const float4* up = (const float4*)&u[(size_t)(r0 + lr) * 8];
            float4 v0 = up[0], v1 = up[1];
            vv[0] = v0.x; vv[1] = v0.y; vv[2] = v0.z; vv[3] = v0.w;
            vv[4] = v1.x; vv[5] = v1.y; vv[6] = v1.z; vv[7] = v1.w;
            split8(vv, a_h[0], a_m[0], a_l[0]);
            const float4* up2 = (const float4*)&u[(size_t)(r0 + 16 + lr) * 8];
            float4 w0 = up2[0], w1 = up2[1];
            vv[0] = w0.x; vv[1] = w0.y; vv[2] = w0.z; vv[3] = w0.w;
            vv[4] = w1.x; vv[5] = w1.y; vv[6] = w1.z; vv[7] = w1.w;
            split8(vv, a_h[1], a_m[1], a_l[1]);
        } else {
            short8 z = {0, 0, 0, 0, 0, 0, 0, 0};
            a_h[0] = z; a_h[1] = z; a_m[0] = z; a_m[1] = z; a_l[0] = z; a_l[1] = z;
        }
        short8 b_h[4], b_m[4], b_l[4];
#pragma unroll
        for (int nf = 0; nf < 4; ++nf) {
            const int off = fb[nf] + 8 * 512;
            b_h[nf] = *(const short8*)&Bh[off];
            b_m[nf] = *(const short8*)&Bm[off];
            b_l[nf] = *(const short8*)&Bl[off];
        }
#pragma unroll
        M2_MFMA6()
    }
    for (int kt = 9; kt < 11; ++kt) { // w tiles (8-product)
        const int wc = (kt - 9) * 32 + lk;
        short8 a_h[2], a_m[2], a_l[2];
        {
            float vv[8];
            const float4* wp = (const float4*)&wg[(size_t)(r0 + lr) * 64 + wc];
            float4 v0 = wp[0], v1 = wp[1];
            vv[0] = v0.x; vv[1] = v0.y; vv[2] = v0.z; vv[3] = v0.w;
            vv[4] = v1.x; vv[5] = v1.y; vv[6] = v1.z; vv[7] = v1.w;
            split8(vv, a_h[0], a_m[0], a_l[0]);
            const float4* wp2 = (const float4*)&wg[(size_t)(r0 + 16 + lr) * 64 + wc];
            float4 w0 = wp2[0], w1 = wp2[1];
            vv[0] = w0.x; vv[1] = w0.y; vv[2] = w0.z; vv[3] = w0.w;
            vv[4] = w1.x; vv[5] = w1.y; vv[6] = w1.z; vv[7] = w1.w;
            split8(vv, a_h[1], a_m[1], a_l[1]);
        }
        short8 b_h[4], b_m[4], b_l[4];
#pragma unroll
        for (int nf = 0; nf < 4; ++nf) {
            const int off = fb[nf] + kt * 512;
            b_h[nf] = *(const short8*)&Bh[off];
            b_m[nf] = *(const short8*)&Bm[off];
            b_l[nf] = *(const short8*)&Bl[off];
        }
#pragma unroll
        for (int nf = 0; nf < 4; ++nf) {
#pragma unroll
            for (int m = 0; m < 2; ++m) {
                acc[m][nf] = __builtin_amdgcn_mfma_f32_16x16x32_bf16(a_h[m], b_h[nf], acc[m][nf], 0, 0, 0);
                acc[m][nf] = __builtin_amdgcn_mfma_f32_16x16x32_bf16(a_m[m], b_h[nf], acc[m][nf], 0, 0, 0);
                acc[m][nf] = __builtin_amdgcn_mfma_f32_16x16x32_bf16(a_h[m], b_m[nf], acc[m][nf], 0, 0, 0);
                acc[m][nf] = __builtin_amdgcn_mfma_f32_16x16x32_bf16(a_l[m], b_h[nf], acc[m][nf], 0, 0, 0);
                acc[m][nf] = __builtin_amdgcn_mfma_f32_16x16x32_bf16(a_m[m], b_m[nf], acc[m][nf], 0, 0, 0);
                acc[m][nf] = __builtin_amdgcn_mfma_f32_16x16x32_bf16(a_h[m], b_l[nf], acc[m][nf], 0, 0, 0);
                acc[m][nf] = __builtin_amdgcn_mfma_f32_16x16x32_bf16(a_m[m], b_l[nf], acc[m][nf], 0, 0, 0);
                acc[m][nf] = __builtin_amdgcn_mfma_f32_16x16x32_bf16(a_l[m], b_m[nf], acc[m][nf], 0, 0, 0);
            }
        }
    }
#pragma unroll
    for (int m = 0; m < 2; ++m)
#pragma unroll
        for (int nf = 0; nf < 4; ++nf)
#pragma unroll
            for (int j = 0; j < 4; ++j)
                out[(size_t)(r0 + m * 16 + lg * 4 + j) * 256 + n0 + nf * 16 + lr] = acc[m][nf][j];
}

extern "C" void kernel_launch(void* const* d_in, const int* in_sizes, int n_in,
                              void* d_out, int out_size, void* d_ws, size_t ws_size,
                              hipStream_t stream) {
    const float* x   = (const float*)d_in[0];
    const float* u   = (const float*)d_in[1];
    const float* Xm  = (const float*)d_in[2];
    const float* Um  = (const float*)d_in[3];
    const float* Y1  = (const float*)d_in[4];
    const float* XPm = (const float*)d_in[5];
    const float* B2  = (const float*)d_in[6];
    const float* D12 = (const float*)d_in[7];
    const float* bv  = (const float*)d_in[8];
    float* out = (float*)d_out;
    float* ws  = (float*)d_ws;

    float* H    = ws + WS_H;
    float* C0   = ws + WS_C;
    float* C1   = ws + WS_C2;
    float* Y    = ws + WS_Y;
    float* RHS  = ws + WS_RHS;
    float* D11g = ws + WS_D11;
    float* E0   = ws + WS_E0;
    float* E1   = ws + WS_E1;
    unsigned short* Bh  = (unsigned short*)(ws + WS_WFH);
    unsigned short* Bm  = (unsigned short*)(ws + WS_WFM);
    unsigned short* Bl  = (unsigned short*)(ws + WS_WFL);
    unsigned short* Bbh = (unsigned short*)(ws + WS_BBH);
    unsigned short* Bbm = (unsigned short*)(ws + WS_BBM);
    unsigned short* Bbl = (unsigned short*)(ws + WS_BBL);
    float* wg = ws + WS_WG;

    k_build<<<656, 256, 0, stream>>>(Xm, XPm, H, C0);
    k_derived<<<442, 256, 0, stream>>>(H, Um, Y1, B2, D12, Y, RHS, D11g,
                                       Bh, Bm, Bl, Bbh, Bbm, Bbl, C0, E0);
    k_base<<<2048, 256, 0, stream>>>(x, u, Bbh, Bbm, Bbl, bv, wg);
    k_rec<<<256, 256, 0, stream>>>(wg, D11g);
    k_gjS<<<16, 256, 0, stream>>>(C0, C1, E0, E1, 0, 1);
    k_gjS<<<16, 256, 0, stream>>>(C1, C0, E1, E0, 1, 2);
    k_gjS<<<16, 256, 0, stream>>>(C0, C1, E0, E1, 2, 3);
    k_gjS<<<16, 256, 0, stream>>>(C1, C0, E1, E0, 3, -1);
    k_apply2<<<20, 256, 0, stream>>>(C0, Y, RHS, Bh, Bm, Bl);
    k_m2<<<2048, 256, 0, stream>>>(x, wg, u, Bh, Bm, Bl, out);
}